// Round 12
// baseline (437.064 us; speedup 1.0000x reference)
//
#include <hip/hip_runtime.h>
#include <hip/hip_bf16.h>
#include <float.h>
#include <math.h>

typedef __hip_bfloat16 bf16;
typedef __attribute__((ext_vector_type(8))) short short8;
typedef __attribute__((ext_vector_type(4))) float f32x4;

__device__ __forceinline__ float bf2f(bf16 v){ return __bfloat162float(v); }
__device__ __forceinline__ void stv(float* p, float v){ *p = v; }
__device__ __forceinline__ void stv(bf16* p, float v){ *p = __float2bfloat16(v); }
__device__ __forceinline__ float nanfix(float v){
  if (v != v) return 0.f;
  return fminf(fmaxf(v, -FLT_MAX), FLT_MAX);
}
__device__ __forceinline__ unsigned short f2bu(float f){
  unsigned u = __float_as_uint(f);
  unsigned r = u + 0x7FFFu + ((u>>16)&1u);
  return (unsigned short)(r>>16);
}
template<int VEC>
__device__ __forceinline__ void ldbf(const bf16* p, float (&o)[VEC]){
  if constexpr (VEC==4){
    ushort4 r = *(const ushort4*)p;
    o[0]=__uint_as_float((unsigned)r.x<<16); o[1]=__uint_as_float((unsigned)r.y<<16);
    o[2]=__uint_as_float((unsigned)r.z<<16); o[3]=__uint_as_float((unsigned)r.w<<16);
  } else {
    ushort2 r = *(const ushort2*)p;
    o[0]=__uint_as_float((unsigned)r.x<<16); o[1]=__uint_as_float((unsigned)r.y<<16);
  }
}

// ---------------- edge degree + parallel scan + scatter ----------------
__global__ void k_deg(const int* __restrict__ tgt, int* __restrict__ deg, int E){
  int e = blockIdx.x*blockDim.x + threadIdx.x;
  if (e < E) atomicAdd(&deg[tgt[e]], 1);
}

__global__ void k_scan1(const int* __restrict__ deg, int* __restrict__ bsum, int N){
  __shared__ int sm[256];
  int i = blockIdx.x*256 + threadIdx.x;
  sm[threadIdx.x] = (i < N) ? deg[i] : 0;
  __syncthreads();
  for (int off = 128; off > 0; off >>= 1){
    if (threadIdx.x < off) sm[threadIdx.x] += sm[threadIdx.x + off];
    __syncthreads();
  }
  if (threadIdx.x == 0) bsum[blockIdx.x] = sm[0];
}

__global__ void k_scan2(int* __restrict__ bsum, int NB){
  __shared__ int sm[1024];
  int tid = threadIdx.x;
  sm[tid] = (tid < NB) ? bsum[tid] : 0;
  __syncthreads();
  for (int off = 1; off < 1024; off <<= 1){
    int t = (tid >= off) ? sm[tid-off] : 0;
    __syncthreads();
    sm[tid] += t;
    __syncthreads();
  }
  if (tid < NB) bsum[tid] = (tid == 0) ? 0 : sm[tid-1];   // exclusive block offsets
}

__global__ void k_scan3(const int* __restrict__ deg, const int* __restrict__ bsum,
                        int* __restrict__ offs, int N){
  __shared__ int sm[256];
  int tid = threadIdx.x;
  int i = blockIdx.x*256 + tid;
  int v = (i < N) ? deg[i] : 0;
  sm[tid] = v; __syncthreads();
  for (int off = 1; off < 256; off <<= 1){
    int t = (tid >= off) ? sm[tid-off] : 0;
    __syncthreads();
    sm[tid] += t;
    __syncthreads();
  }
  if (i < N) offs[i+1] = bsum[blockIdx.x] + sm[tid];
  if (i == 0) offs[0] = 0;
}

__global__ void k_scatter(const int* __restrict__ src, const int* __restrict__ tgt,
                          const int* __restrict__ offs, int* __restrict__ cnt,
                          int* __restrict__ ssrc, int E){
  int e = blockIdx.x*blockDim.x + threadIdx.x;
  if (e < E){
    int t = tgt[e];
    int pos = offs[t] + atomicAdd(&cnt[t], 1);
    ssrc[pos] = src[e];
  }
}

// ---------------- fused setup: weight repacks + x conversion (one dispatch) ----------------
__device__ __forceinline__ void rp_pqT(const float* preW, const float* preB,
                                       bf16* WpqT, float* bpq, int K, int F, int idx){
  int NC = 4*F;
  int total = 2*NC*K;
  if (idx < total){
    int j = idx/K, c = idx%K;
    int half = j/NC, jj = j%NC, t = jj/F, f = jj%F;
    WpqT[idx] = __float2bfloat16(preW[(t*2*K + half*K + c)*F + f]);
  }
  if (idx < 2*NC) bpq[idx] = (idx < NC) ? preB[idx] : 0.f;
}
__device__ __forceinline__ void rp_xT(const float* postW, const float* postB,
                                      bf16* WxT, float* bpost, int KX, int F, int idx){
  int NC = 4*F; int KP = KX + 12*F;
  if (idx < NC*KX){
    int j = idx/KX, c = idx%KX, t = j/F, f = j%F;
    WxT[idx] = __float2bfloat16(postW[(t*KP + c)*F + f]);
  }
  if (idx < NC) bpost[idx] = postB[idx];
}
__device__ __forceinline__ void rp_agg3(const float* postW, bf16* Wagg3,
                                        int KX, int F, int idx){
  int K4F = 4*F; int KP = KX + 12*F;
  int total = 4*3*F*K4F;
  if (idx < total){
    int k = idx % K4F; int r = idx / K4F;
    int zr = r % (3*F); int t = r / (3*F);
    int s = zr / F, f = zr % F;
    Wagg3[idx] = __float2bfloat16(postW[((size_t)(t*KP + KX + s*K4F + k))*F + f]);
  }
}
__device__ __forceinline__ void rp_linT(const float* linW, bf16* WlinT,
                                        int K, int NC, int idx){
  if (idx < NC*K){
    int j = idx/K, c = idx%K;
    WlinT[idx] = __float2bfloat16(linW[c*NC + j]);
  }
}

struct SetupArgs {
  const float *pre1W, *pre1b, *post1W, *post1b, *lin1W;
  const float *pre2W, *pre2b, *post2W, *post2b, *lin2W;
  const float *x;
  bf16 *WpqT1, *WxT1, *Wagg31, *lin1WT;
  bf16 *WpqT2, *WxT2, *Wagg32, *lin2WT;
  bf16 *x_bf;
  float *bpq1, *bpost1, *bpq2, *bpost2;
  int nx4;       // N*IN/4
  int gstride;   // gridDim.x*256
};

__global__ void k_setup(SetupArgs a){
  int idx = blockIdx.x*256 + threadIdx.x;
  switch (blockIdx.y){
    case 0: rp_pqT (a.pre1W, a.pre1b, a.WpqT1, a.bpq1, 128, 64, idx); break;
    case 1: rp_xT  (a.post1W, a.post1b, a.WxT1, a.bpost1, 128, 64, idx); break;
    case 2: rp_agg3(a.post1W, a.Wagg31, 128, 64, idx); break;
    case 3: rp_linT(a.lin1W, a.lin1WT, 256, 256, idx); break;
    case 4: rp_pqT (a.pre2W, a.pre2b, a.WpqT2, a.bpq2, 256, 32, idx); break;
    case 5: rp_xT  (a.post2W, a.post2b, a.WxT2, a.bpost2, 256, 32, idx); break;
    case 6: rp_agg3(a.post2W, a.Wagg32, 256, 32, idx); break;
    case 7: rp_linT(a.lin2W, a.lin2WT, 128, 128, idx); break;
    case 8:
      for (int i = idx; i < a.nx4; i += a.gstride){
        float4 v = *(const float4*)(a.x + (size_t)i*4);
        ushort4 o = make_ushort4(f2bu(v.x), f2bu(v.y), f2bu(v.z), f2bu(v.w));
        *(ushort4*)(a.x_bf + (size_t)i*4) = o;
      }
      break;
  }
}

// ---------------- MFMA GEMM: C[N, *] = A[N,K](bf16) @ Bt[NC,K]^T (bf16) ----------------
// 64x64 tile, 4 waves, each wave 32x32 via 2x2 mfma_f32_16x16x32_bf16.  (R8 proven config)
template<typename TO>
__global__ __launch_bounds__(256) void k_mgemm(
    const bf16* __restrict__ A, int lda,
    const bf16* __restrict__ Bt,
    const float* __restrict__ bias,
    TO* __restrict__ Cout, int ldc,
    int N, int K, int NC)
{
  __shared__ __align__(16) bf16 As[64*40];
  __shared__ __align__(16) bf16 Bs[64*40];
  int n0 = blockIdx.y*64;
  int j0 = blockIdx.x*64;
  int tid = threadIdx.x;
  int srow = tid>>2, skoff = (tid&3)*8;
  int wave = tid>>6, lane = tid&63;
  int wy = (wave>>1)*32, wx = (wave&1)*32;
  int l15 = lane&15, q = lane>>4;
  f32x4 acc[2][2] = {};
  for (int k0 = 0; k0 < K; k0 += 32){
    uint4 av = {0,0,0,0};
    int ar = n0 + srow;
    if (ar < N) av = *(const uint4*)(A + (size_t)ar*lda + k0 + skoff);
    *(uint4*)&As[srow*40 + skoff] = av;
    uint4 bv = {0,0,0,0};
    int br = j0 + srow;
    if (br < NC) bv = *(const uint4*)(Bt + (size_t)br*K + k0 + skoff);
    *(uint4*)&Bs[srow*40 + skoff] = bv;
    __syncthreads();
    short8 af[2], bfr[2];
    #pragma unroll
    for (int i = 0; i < 2; i++){
      af[i]  = *(const short8*)&As[(wy + i*16 + l15)*40 + q*8];
      bfr[i] = *(const short8*)&Bs[(wx + i*16 + l15)*40 + q*8];
    }
    #pragma unroll
    for (int mi = 0; mi < 2; mi++)
      #pragma unroll
      for (int ni = 0; ni < 2; ni++)
        acc[mi][ni] = __builtin_amdgcn_mfma_f32_16x16x32_bf16(af[mi], bfr[ni], acc[mi][ni], 0, 0, 0);
    __syncthreads();
  }
  #pragma unroll
  for (int mi = 0; mi < 2; mi++){
    #pragma unroll
    for (int ni = 0; ni < 2; ni++){
      #pragma unroll
      for (int r = 0; r < 4; r++){
        int n  = n0 + wy + mi*16 + q*4 + r;
        int jj = j0 + wx + ni*16 + l15;
        if (n < N && jj < NC){
          float v = acc[mi][ni][r] + bias[jj];
          stv(&Cout[(size_t)n*ldc + jj], v);
        }
      }
    }
  }
}

// ---------------- fused post GEMM, barrier-free: fragments loaded direct from global ----------------
// All B matrices are L2-resident; A (x_bf/agg) is L2-resident. No LDS, no __syncthreads.
// grid (1, NB, T). COLS = F per tower; K4F = 4*COLS; agg row stride = 16*COLS.
template<int COLS, int KX>
__global__ __launch_bounds__(256) void k_postx(
    const bf16* __restrict__ X,        // [N, KX]
    const bf16* __restrict__ agg,      // [N, 16*COLS]
    const bf16* __restrict__ WxT,      // [4*COLS, KX]  (tower-blocked rows)
    const bf16* __restrict__ Wagg3,    // [T][3*COLS][K4F]
    const float* __restrict__ bias,    // [4*COLS]
    const float* __restrict__ scal,
    bf16* __restrict__ Cout, int ldc, int N)
{
  constexpr int K4F = 4*COLS;
  constexpr int ROWS3 = 3*COLS;
  constexpr int NI = COLS/32;          // 2 (COLS=64) or 1 (COLS=32)
  constexpr int LDA_AGG = 16*COLS;
  int z = blockIdx.z;
  int n0 = blockIdx.y*64;
  int tid = threadIdx.x;
  int wave = tid>>6, lane = tid&63;
  int wy = (wave>>1)*32;
  int wx = (wave&1)*(COLS/2);
  int l15 = lane&15, q = lane>>4;
  const short8 zfrag = {};
  f32x4 accx[2][NI] = {};
  f32x4 acc[2][NI][3] = {};
  int r0 = n0 + wy + l15;            // A row, mi=0
  int r1 = r0 + 16;                  // A row, mi=1
  bool v0 = r0 < N, v1 = r1 < N;
  // ---- phase 1: X @ WxT (tower slice), fragments direct from global ----
  {
    const bf16* A0 = X + (size_t)(v0 ? r0 : 0)*KX + q*8;
    const bf16* A1 = X + (size_t)(v1 ? r1 : 0)*KX + q*8;
    const bf16* B0 = WxT + ((size_t)z*COLS + wx + l15)*KX + q*8;
    #pragma unroll
    for (int k0 = 0; k0 < KX; k0 += 32){
      short8 a0 = v0 ? *(const short8*)(A0 + k0) : zfrag;
      short8 a1 = v1 ? *(const short8*)(A1 + k0) : zfrag;
      #pragma unroll
      for (int ni = 0; ni < NI; ni++){
        short8 b = *(const short8*)(B0 + (size_t)ni*16*KX + k0);
        accx[0][ni] = __builtin_amdgcn_mfma_f32_16x16x32_bf16(a0, b, accx[0][ni], 0, 0, 0);
        accx[1][ni] = __builtin_amdgcn_mfma_f32_16x16x32_bf16(a1, b, accx[1][ni], 0, 0, 0);
      }
    }
  }
  // ---- phase 2: agg @ Wagg3 (3 scaler blocks), fragments direct from global ----
  {
    const bf16* A0 = agg + (size_t)(v0 ? r0 : 0)*LDA_AGG + z*K4F + q*8;
    const bf16* A1 = agg + (size_t)(v1 ? r1 : 0)*LDA_AGG + z*K4F + q*8;
    const bf16* B0 = Wagg3 + ((size_t)z*ROWS3 + wx + l15)*K4F + q*8;
    #pragma unroll
    for (int k0 = 0; k0 < K4F; k0 += 32){
      short8 a0 = v0 ? *(const short8*)(A0 + k0) : zfrag;
      short8 a1 = v1 ? *(const short8*)(A1 + k0) : zfrag;
      #pragma unroll
      for (int s = 0; s < 3; s++){
        #pragma unroll
        for (int ni = 0; ni < NI; ni++){
          short8 b = *(const short8*)(B0 + (size_t)(s*COLS + ni*16)*K4F + k0);
          acc[0][ni][s] = __builtin_amdgcn_mfma_f32_16x16x32_bf16(a0, b, acc[0][ni][s], 0, 0, 0);
          acc[1][ni][s] = __builtin_amdgcn_mfma_f32_16x16x32_bf16(a1, b, acc[1][ni][s], 0, 0, 0);
        }
      }
    }
  }
  #pragma unroll
  for (int mi = 0; mi < 2; mi++){
    #pragma unroll
    for (int ni = 0; ni < NI; ni++){
      int jj = wx + ni*16 + l15;
      int jg = z*COLS + jj;
      float bj = bias[jg];
      #pragma unroll
      for (int r = 0; r < 4; r++){
        int n = n0 + wy + mi*16 + q*4 + r;
        if (n < N){
          float s1 = scal[2*n], s2 = scal[2*n+1];
          float v = bj + accx[mi][ni][r]
                  + acc[mi][ni][0][r] + s1*acc[mi][ni][1][r] + s2*acc[mi][ni][2][r];
          Cout[(size_t)n*ldc + jg] = __float2bfloat16(v);
        }
      }
    }
  }
}

// ---------------- per-node PNA aggregation -> agg [N, T*4F] bf16 + scal ----------------
// node per wave; 8-edge unroll for gather MLP (latency-bound kernel).
template<int NC, int F>
__global__ __launch_bounds__(256) void k_agg(const bf16* __restrict__ PQ,
    const int* __restrict__ ssrc, const int* __restrict__ offs,
    const float* __restrict__ avgp,
    bf16* __restrict__ agg, float* __restrict__ scal, int N){
  constexpr int VEC = NC/64;
  int wave = threadIdx.x>>6, lane = threadIdx.x&63;
  int n = blockIdx.x*4 + wave;
  if (n >= N) return;
  int c0 = lane*VEC;
  float p[VEC];
  ldbf<VEC>(PQ + (size_t)n*2*NC + c0, p);
  int s0 = offs[n], s1 = offs[n+1];
  float sum[VEC], sq[VEC], mn[VEC], mx[VEC];
  #pragma unroll
  for (int v=0;v<VEC;v++){ sum[v]=0.f; sq[v]=0.f; mn[v]=FLT_MAX; mx[v]=-FLT_MAX; }
  const bf16* Q = PQ + NC + c0;
  int i = s0;
  for (; i+7 < s1; i += 8){
    int se[8];
    #pragma unroll
    for (int u=0;u<8;u++) se[u] = ssrc[i+u];
    float qv[8][VEC];
    #pragma unroll
    for (int u=0;u<8;u++) ldbf<VEC>(Q + (size_t)se[u]*2*NC, qv[u]);
    #pragma unroll
    for (int u=0;u<8;u++){
      #pragma unroll
      for (int v=0;v<VEC;v++){
        float m = p[v]+qv[u][v];
        sum[v] += m; sq[v] = fmaf(m,m,sq[v]);
        mn[v] = fminf(mn[v], m); mx[v] = fmaxf(mx[v], m);
      }
    }
  }
  for (; i+3 < s1; i += 4){
    int se[4];
    #pragma unroll
    for (int u=0;u<4;u++) se[u] = ssrc[i+u];
    float qv[4][VEC];
    #pragma unroll
    for (int u=0;u<4;u++) ldbf<VEC>(Q + (size_t)se[u]*2*NC, qv[u]);
    #pragma unroll
    for (int u=0;u<4;u++){
      #pragma unroll
      for (int v=0;v<VEC;v++){
        float m = p[v]+qv[u][v];
        sum[v] += m; sq[v] = fmaf(m,m,sq[v]);
        mn[v] = fminf(mn[v], m); mx[v] = fmaxf(mx[v], m);
      }
    }
  }
  for (; i < s1; i++){
    int sa = ssrc[i];
    float qa[VEC];
    ldbf<VEC>(Q + (size_t)sa*2*NC, qa);
    #pragma unroll
    for (int v=0;v<VEC;v++){
      float m = p[v]+qa[v];
      sum[v]+=m; sq[v]=fmaf(m,m,sq[v]); mn[v]=fminf(mn[v],m); mx[v]=fmaxf(mx[v],m);
    }
  }
  int deg = s1-s0;
  float degc = fmaxf((float)deg, 1.f);
  unsigned short um[VEC], un[VEC], ux[VEC], us[VEC];
  #pragma unroll
  for (int v=0;v<VEC;v++){
    float mean = sum[v]/degc;
    float var = fmaxf(sq[v]/degc - mean*mean, 0.f);
    float sd = sqrtf(var + 1e-5f);
    float mnv = deg>0 ? mn[v] : 0.f;
    float mxv = deg>0 ? mx[v] : 0.f;
    um[v]=f2bu(mean); un[v]=f2bu(mnv); ux[v]=f2bu(mxv); us[v]=f2bu(sd);
  }
  int t = c0 / F, f0 = c0 % F;
  bf16* base = agg + (size_t)n*4*NC + (size_t)t*4*F + f0;
  if constexpr (VEC==4){
    *(ushort4*)(base)       = make_ushort4(um[0],um[1],um[2],um[3]);
    *(ushort4*)(base + F)   = make_ushort4(un[0],un[1],un[2],un[3]);
    *(ushort4*)(base + 2*F) = make_ushort4(ux[0],ux[1],ux[2],ux[3]);
    *(ushort4*)(base + 3*F) = make_ushort4(us[0],us[1],us[2],us[3]);
  } else {
    *(ushort2*)(base)       = make_ushort2(um[0],um[1]);
    *(ushort2*)(base + F)   = make_ushort2(un[0],un[1]);
    *(ushort2*)(base + 2*F) = make_ushort2(ux[0],ux[1]);
    *(ushort2*)(base + 3*F) = make_ushort2(us[0],us[1]);
  }
  if (lane==0){
    float dlog = logf(degc + 1.f);
    float avg = *avgp;
    scal[2*n]   = dlog/avg;
    scal[2*n+1] = avg/dlog;
  }
}

// ---------------- batch norm: two-phase, no hot atomics ----------------
template<int C>
__global__ __launch_bounds__(256) void k_bn_part(const float* __restrict__ h,
                                                 float* __restrict__ part, int N){
  constexpr int C4 = C/4;
  constexpr int RG = 256/C4;
  constexpr int RPB = 128;
  int c4 = threadIdx.x % C4, rg = threadIdx.x / C4;
  int n0 = blockIdx.x*RPB;
  int n1 = min(n0 + RPB, N);
  float4 s = {0,0,0,0}, q = {0,0,0,0};
  for (int n = n0 + rg; n < n1; n += RG){
    float4 v = *(const float4*)(h + (size_t)n*C + c4*4);
    v.x = nanfix(v.x); v.y = nanfix(v.y); v.z = nanfix(v.z); v.w = nanfix(v.w);
    s.x += v.x; s.y += v.y; s.z += v.z; s.w += v.w;
    q.x += v.x*v.x; q.y += v.y*v.y; q.z += v.z*v.z; q.w += v.w*v.w;
  }
  __shared__ float4 ssum[256], ssq[256];
  ssum[threadIdx.x] = s; ssq[threadIdx.x] = q;
  __syncthreads();
  if (rg == 0){
    #pragma unroll
    for (int g = 1; g < RG; g++){
      float4 o = ssum[g*C4 + c4];
      s.x += o.x; s.y += o.y; s.z += o.z; s.w += o.w;
      float4 p = ssq[g*C4 + c4];
      q.x += p.x; q.y += p.y; q.z += p.z; q.w += p.w;
    }
    float* dst = part + (size_t)blockIdx.x*2*C;
    *(float4*)(dst + c4*4)     = s;
    *(float4*)(dst + C + c4*4) = q;
  }
}

template<int C>
__global__ __launch_bounds__(256) void k_bn_final(const float* __restrict__ part, int PB,
                                                  float* __restrict__ stats){
  int c = blockIdx.x*256 + threadIdx.x;
  if (c >= 2*C) return;
  int CH = gridDim.y;
  int per = (PB + CH - 1)/CH;
  int p0 = blockIdx.y*per, p1 = min(p0 + per, PB);
  float acc = 0.f;
  int p = p0;
  for (; p+4 <= p1; p += 4){
    acc += part[(size_t)p*2*C + c] + part[(size_t)(p+1)*2*C + c]
         + part[(size_t)(p+2)*2*C + c] + part[(size_t)(p+3)*2*C + c];
  }
  for (; p < p1; p++) acc += part[(size_t)p*2*C + c];
  atomicAdd(&stats[c], acc);
}

template<typename TO, int C>
__global__ void k_bn_apply(const float* __restrict__ h, const float* __restrict__ stats,
     const float* __restrict__ g, const float* __restrict__ b,
     TO* __restrict__ out, int N){
  int idx = blockIdx.x*blockDim.x + threadIdx.x;   // quad index
  if (idx >= N*(C/4)) return;
  int c = (idx % (C/4))*4;
  float fn = (float)N;
  float4 v = *(const float4*)(h + (size_t)idx*4);
  float r[4];
  #pragma unroll
  for (int k = 0; k < 4; k++){
    float m = stats[c+k]/fn;
    float var = fmaxf(stats[C+c+k]/fn - m*m, 0.f);
    float inv = rsqrtf(var + 1e-5f);
    float vv = nanfix(((const float*)&v)[k]);
    r[k] = fmaxf(g[c+k]*(vv - m)*inv + b[c+k], 0.f);
  }
  if constexpr (sizeof(TO) == 4){
    float4 o = {r[0], r[1], r[2], r[3]};
    *(float4*)((float*)out + (size_t)idx*4) = o;
  } else {
    ushort4 o = make_ushort4(f2bu(r[0]), f2bu(r[1]), f2bu(r[2]), f2bu(r[3]));
    *(ushort4*)((bf16*)out + (size_t)idx*4) = o;
  }
}

static inline int cdiv(int a, int b){ return (a + b - 1)/b; }

extern "C" void kernel_launch(void* const* d_in, const int* in_sizes, int n_in,
                              void* d_out, int out_size, void* d_ws, size_t ws_size,
                              hipStream_t stream){
  const int IN = 128, HID = 256, T = 4, F1 = 64, F2 = 32;
  const int N = in_sizes[0]/IN;
  const int E = in_sizes[1]/2;
  const int NC1 = T*F1;        // 256
  const int NC2 = T*F2;        // 128

  const float* x      = (const float*)d_in[0];
  const int*   ei     = (const int*)  d_in[1];
  const int*   srcE   = ei;
  const int*   tgtE   = ei + E;
  const float* avgp   = (const float*)d_in[2];
  const float* pre1W  = (const float*)d_in[3];
  const float* pre1b  = (const float*)d_in[4];
  const float* post1W = (const float*)d_in[5];
  const float* post1b = (const float*)d_in[6];
  const float* lin1W  = (const float*)d_in[7];
  const float* lin1b  = (const float*)d_in[8];
  const float* bn1g   = (const float*)d_in[9];
  const float* bn1b   = (const float*)d_in[10];
  const float* pre2W  = (const float*)d_in[11];
  const float* pre2b  = (const float*)d_in[12];
  const float* post2W = (const float*)d_in[13];
  const float* post2b = (const float*)d_in[14];
  const float* lin2W  = (const float*)d_in[15];
  const float* lin2b  = (const float*)d_in[16];
  const float* bn2g   = (const float*)d_in[17];
  const float* bn2b   = (const float*)d_in[18];

  // ---- workspace carve ----
  char* w = (char*)d_ws;
  auto alloc = [&](size_t bytes)->void*{
    void* p = (void*)w; w += (bytes + 255) & ~(size_t)255; return p;
  };
  bf16* WpqT1  = (bf16*)alloc((size_t)2*NC1*IN*2);    float* bpq1   = (float*)alloc(2*NC1*4);
  bf16* WxT1   = (bf16*)alloc((size_t)NC1*IN*2);      float* bpost1 = (float*)alloc(NC1*4);
  bf16* Wagg31 = (bf16*)alloc((size_t)T*3*F1*4*F1*2);
  bf16* lin1WT = (bf16*)alloc((size_t)HID*NC1*2);
  bf16* WpqT2  = (bf16*)alloc((size_t)2*NC2*HID*2);   float* bpq2   = (float*)alloc(2*NC2*4);
  bf16* WxT2   = (bf16*)alloc((size_t)NC2*HID*2);     float* bpost2 = (float*)alloc(NC2*4);
  bf16* Wagg32 = (bf16*)alloc((size_t)T*3*F2*4*F2*2);
  bf16* lin2WT = (bf16*)alloc((size_t)128*NC2*2);
  // zero region: deg_i | cnt | stats (one memset)
  int* deg_i   = (int*)alloc((size_t)N*4);
  int* cnt     = (int*)alloc((size_t)N*4);
  float* stats = (float*)alloc(1024*4);
  size_t zbytes = (size_t)((char*)stats - (char*)deg_i) + 1024*4;
  int* offs    = (int*)alloc((size_t)(N+1)*4);
  int* bsum    = (int*)alloc((size_t)cdiv(N,256)*4);
  int* ssrc    = (int*)alloc((size_t)E*4);
  bf16* x_bf   = (bf16*)alloc((size_t)N*IN*2);
  bf16* PQ     = (bf16*)alloc((size_t)N*512*2);
  bf16* aggb   = (bf16*)alloc((size_t)N*4*NC1*2);    // L2 reuses prefix [N, 4*NC2]
  float* scal  = (float*)alloc((size_t)N*2*4);
  bf16* postbb = (bf16*)alloc((size_t)N*256*2);
  float* hpre  = (float*)alloc((size_t)N*256*4);
  bf16* h1b    = (bf16*)alloc((size_t)N*256*2);
  int PB = cdiv(N,128);
  float* part  = (float*)alloc((size_t)PB*512*4);

  hipMemsetAsync(deg_i, 0, zbytes, stream);

  // ---- setup: all weight repacks + x conversion (one dispatch) ----
  int sgx = cdiv(T*3*F1*4*F1, 256);   // 768 blocks covers the largest segment
  SetupArgs sa = { pre1W, pre1b, post1W, post1b, lin1W,
                   pre2W, pre2b, post2W, post2b, lin2W,
                   x,
                   WpqT1, WxT1, Wagg31, lin1WT,
                   WpqT2, WxT2, Wagg32, lin2WT,
                   x_bf,
                   bpq1, bpost1, bpq2, bpost2,
                   N*IN/4, sgx*256 };
  k_setup<<<dim3(sgx, 9),256,0,stream>>>(sa);

  // ---- counting sort of edges by target (parallel scan) ----
  int NBs = cdiv(N,256);
  k_deg<<<cdiv(E,256),256,0,stream>>>(tgtE, deg_i, E);
  k_scan1<<<NBs,256,0,stream>>>(deg_i, bsum, N);
  k_scan2<<<1,1024,0,stream>>>(bsum, NBs);
  k_scan3<<<NBs,256,0,stream>>>(deg_i, bsum, offs, N);
  k_scatter<<<cdiv(E,256),256,0,stream>>>(srcE, tgtE, offs, cnt, ssrc, E);

  int NB = cdiv(N,64);

  // ================= Layer 1 =================
  k_mgemm<bf16><<<dim3(8,NB),256,0,stream>>>(x_bf, IN, WpqT1, bpq1, PQ, 512, N, IN, 512);
  k_agg<256,64><<<cdiv(N,4),256,0,stream>>>(PQ, ssrc, offs, avgp, aggb, scal, N);
  k_postx<64,128><<<dim3(1,NB,T),256,0,stream>>>(x_bf, aggb, WxT1, Wagg31, bpost1, scal,
                                                 postbb, NC1, N);
  k_mgemm<float><<<dim3(4,NB),256,0,stream>>>(postbb, NC1, lin1WT, lin1b, hpre, HID, N, NC1, HID);
  k_bn_part<256><<<PB,256,0,stream>>>(hpre, part, N);
  k_bn_final<256><<<dim3(2,4),256,0,stream>>>(part, PB, stats);
  k_bn_apply<bf16,256><<<cdiv(N*64,256),256,0,stream>>>(hpre, stats, bn1g, bn1b, h1b, N);

  // ================= Layer 2 =================
  k_mgemm<bf16><<<dim3(4,NB),256,0,stream>>>(h1b, HID, WpqT2, bpq2, PQ, 256, N, HID, 256);
  k_agg<128,32><<<cdiv(N,4),256,0,stream>>>(PQ, ssrc, offs, avgp, aggb, scal, N);
  k_postx<32,256><<<dim3(1,NB,T),256,0,stream>>>(h1b, aggb, WxT2, Wagg32, bpost2, scal,
                                                 postbb, NC2, N);
  k_mgemm<float><<<dim3(2,NB),256,0,stream>>>(postbb, NC2, lin2WT, lin2b, hpre, 128, N, NC2, 128);
  k_bn_part<128><<<PB,256,0,stream>>>(hpre, part, N);
  k_bn_final<128><<<dim3(1,4),256,0,stream>>>(part, PB, stats + 512);
  k_bn_apply<float,128><<<cdiv(N*32,256),256,0,stream>>>(hpre, stats + 512, bn2g, bn2b, (float*)d_out, N);
}

// Round 13
// 381.742 us; speedup vs baseline: 1.1449x; 1.1449x over previous
//
#include <hip/hip_runtime.h>
#include <hip/hip_bf16.h>
#include <float.h>
#include <math.h>

typedef __hip_bfloat16 bf16;
typedef __attribute__((ext_vector_type(8))) short short8;
typedef __attribute__((ext_vector_type(4))) float f32x4;

__device__ __forceinline__ float bf2f(bf16 v){ return __bfloat162float(v); }
__device__ __forceinline__ void stv(float* p, float v){ *p = v; }
__device__ __forceinline__ void stv(bf16* p, float v){ *p = __float2bfloat16(v); }
__device__ __forceinline__ float nanfix(float v){
  if (v != v) return 0.f;
  return fminf(fmaxf(v, -FLT_MAX), FLT_MAX);
}
__device__ __forceinline__ unsigned short f2bu(float f){
  unsigned u = __float_as_uint(f);
  unsigned r = u + 0x7FFFu + ((u>>16)&1u);
  return (unsigned short)(r>>16);
}
template<int VEC>
__device__ __forceinline__ void ldbf(const bf16* p, float (&o)[VEC]){
  if constexpr (VEC==4){
    ushort4 r = *(const ushort4*)p;
    o[0]=__uint_as_float((unsigned)r.x<<16); o[1]=__uint_as_float((unsigned)r.y<<16);
    o[2]=__uint_as_float((unsigned)r.z<<16); o[3]=__uint_as_float((unsigned)r.w<<16);
  } else {
    ushort2 r = *(const ushort2*)p;
    o[0]=__uint_as_float((unsigned)r.x<<16); o[1]=__uint_as_float((unsigned)r.y<<16);
  }
}

// ---------------- edge degree + parallel scan + scatter ----------------
__global__ void k_deg(const int* __restrict__ tgt, int* __restrict__ deg, int E){
  int e = blockIdx.x*blockDim.x + threadIdx.x;
  if (e < E) atomicAdd(&deg[tgt[e]], 1);
}

__global__ void k_scan1(const int* __restrict__ deg, int* __restrict__ bsum, int N){
  __shared__ int sm[256];
  int i = blockIdx.x*256 + threadIdx.x;
  sm[threadIdx.x] = (i < N) ? deg[i] : 0;
  __syncthreads();
  for (int off = 128; off > 0; off >>= 1){
    if (threadIdx.x < off) sm[threadIdx.x] += sm[threadIdx.x + off];
    __syncthreads();
  }
  if (threadIdx.x == 0) bsum[blockIdx.x] = sm[0];
}

__global__ void k_scan2(int* __restrict__ bsum, int NB){
  __shared__ int sm[1024];
  int tid = threadIdx.x;
  sm[tid] = (tid < NB) ? bsum[tid] : 0;
  __syncthreads();
  for (int off = 1; off < 1024; off <<= 1){
    int t = (tid >= off) ? sm[tid-off] : 0;
    __syncthreads();
    sm[tid] += t;
    __syncthreads();
  }
  if (tid < NB) bsum[tid] = (tid == 0) ? 0 : sm[tid-1];   // exclusive block offsets
}

__global__ void k_scan3(const int* __restrict__ deg, const int* __restrict__ bsum,
                        int* __restrict__ offs, int N){
  __shared__ int sm[256];
  int tid = threadIdx.x;
  int i = blockIdx.x*256 + tid;
  int v = (i < N) ? deg[i] : 0;
  sm[tid] = v; __syncthreads();
  for (int off = 1; off < 256; off <<= 1){
    int t = (tid >= off) ? sm[tid-off] : 0;
    __syncthreads();
    sm[tid] += t;
    __syncthreads();
  }
  if (i < N) offs[i+1] = bsum[blockIdx.x] + sm[tid];
  if (i == 0) offs[0] = 0;
}

__global__ void k_scatter(const int* __restrict__ src, const int* __restrict__ tgt,
                          const int* __restrict__ offs, int* __restrict__ cnt,
                          int* __restrict__ ssrc, int E){
  int e = blockIdx.x*blockDim.x + threadIdx.x;
  if (e < E){
    int t = tgt[e];
    int pos = offs[t] + atomicAdd(&cnt[t], 1);
    ssrc[pos] = src[e];
  }
}

// ---------------- fused setup: weight repacks + x conversion (one dispatch) ----------------
__device__ __forceinline__ void rp_pqT(const float* preW, const float* preB,
                                       bf16* WpqT, float* bpq, int K, int F, int idx){
  int NC = 4*F;
  int total = 2*NC*K;
  if (idx < total){
    int j = idx/K, c = idx%K;
    int half = j/NC, jj = j%NC, t = jj/F, f = jj%F;
    WpqT[idx] = __float2bfloat16(preW[(t*2*K + half*K + c)*F + f]);
  }
  if (idx < 2*NC) bpq[idx] = (idx < NC) ? preB[idx] : 0.f;
}
__device__ __forceinline__ void rp_xT(const float* postW, const float* postB,
                                      bf16* WxT, float* bpost, int KX, int F, int idx){
  int NC = 4*F; int KP = KX + 12*F;
  if (idx < NC*KX){
    int j = idx/KX, c = idx%KX, t = j/F, f = j%F;
    WxT[idx] = __float2bfloat16(postW[(t*KP + c)*F + f]);
  }
  if (idx < NC) bpost[idx] = postB[idx];
}
__device__ __forceinline__ void rp_agg3(const float* postW, bf16* Wagg3,
                                        int KX, int F, int idx){
  int K4F = 4*F; int KP = KX + 12*F;
  int total = 4*3*F*K4F;
  if (idx < total){
    int k = idx % K4F; int r = idx / K4F;
    int zr = r % (3*F); int t = r / (3*F);
    int s = zr / F, f = zr % F;
    Wagg3[idx] = __float2bfloat16(postW[((size_t)(t*KP + KX + s*K4F + k))*F + f]);
  }
}
__device__ __forceinline__ void rp_linT(const float* linW, bf16* WlinT,
                                        int K, int NC, int idx){
  if (idx < NC*K){
    int j = idx/K, c = idx%K;
    WlinT[idx] = __float2bfloat16(linW[c*NC + j]);
  }
}

struct SetupArgs {
  const float *pre1W, *pre1b, *post1W, *post1b, *lin1W;
  const float *pre2W, *pre2b, *post2W, *post2b, *lin2W;
  const float *x;
  bf16 *WpqT1, *WxT1, *Wagg31, *lin1WT;
  bf16 *WpqT2, *WxT2, *Wagg32, *lin2WT;
  bf16 *x_bf;
  float *bpq1, *bpost1, *bpq2, *bpost2;
  int nx4;       // N*IN/4
  int gstride;   // gridDim.x*256
};

__global__ void k_setup(SetupArgs a){
  int idx = blockIdx.x*256 + threadIdx.x;
  switch (blockIdx.y){
    case 0: rp_pqT (a.pre1W, a.pre1b, a.WpqT1, a.bpq1, 128, 64, idx); break;
    case 1: rp_xT  (a.post1W, a.post1b, a.WxT1, a.bpost1, 128, 64, idx); break;
    case 2: rp_agg3(a.post1W, a.Wagg31, 128, 64, idx); break;
    case 3: rp_linT(a.lin1W, a.lin1WT, 256, 256, idx); break;
    case 4: rp_pqT (a.pre2W, a.pre2b, a.WpqT2, a.bpq2, 256, 32, idx); break;
    case 5: rp_xT  (a.post2W, a.post2b, a.WxT2, a.bpost2, 256, 32, idx); break;
    case 6: rp_agg3(a.post2W, a.Wagg32, 256, 32, idx); break;
    case 7: rp_linT(a.lin2W, a.lin2WT, 128, 128, idx); break;
    case 8:
      for (int i = idx; i < a.nx4; i += a.gstride){
        float4 v = *(const float4*)(a.x + (size_t)i*4);
        ushort4 o = make_ushort4(f2bu(v.x), f2bu(v.y), f2bu(v.z), f2bu(v.w));
        *(ushort4*)(a.x_bf + (size_t)i*4) = o;
      }
      break;
  }
}

// ---------------- MFMA GEMM: C[N, *] = A[N,K](bf16) @ Bt[NC,K]^T (bf16) ----------------
// 64x64 tile, 4 waves, each wave 32x32 via 2x2 mfma_f32_16x16x32_bf16.  (R8 proven config)
template<typename TO>
__global__ __launch_bounds__(256) void k_mgemm(
    const bf16* __restrict__ A, int lda,
    const bf16* __restrict__ Bt,
    const float* __restrict__ bias,
    TO* __restrict__ Cout, int ldc,
    int N, int K, int NC)
{
  __shared__ __align__(16) bf16 As[64*40];
  __shared__ __align__(16) bf16 Bs[64*40];
  int n0 = blockIdx.y*64;
  int j0 = blockIdx.x*64;
  int tid = threadIdx.x;
  int srow = tid>>2, skoff = (tid&3)*8;
  int wave = tid>>6, lane = tid&63;
  int wy = (wave>>1)*32, wx = (wave&1)*32;
  int l15 = lane&15, q = lane>>4;
  f32x4 acc[2][2] = {};
  for (int k0 = 0; k0 < K; k0 += 32){
    uint4 av = {0,0,0,0};
    int ar = n0 + srow;
    if (ar < N) av = *(const uint4*)(A + (size_t)ar*lda + k0 + skoff);
    *(uint4*)&As[srow*40 + skoff] = av;
    uint4 bv = {0,0,0,0};
    int br = j0 + srow;
    if (br < NC) bv = *(const uint4*)(Bt + (size_t)br*K + k0 + skoff);
    *(uint4*)&Bs[srow*40 + skoff] = bv;
    __syncthreads();
    short8 af[2], bfr[2];
    #pragma unroll
    for (int i = 0; i < 2; i++){
      af[i]  = *(const short8*)&As[(wy + i*16 + l15)*40 + q*8];
      bfr[i] = *(const short8*)&Bs[(wx + i*16 + l15)*40 + q*8];
    }
    #pragma unroll
    for (int mi = 0; mi < 2; mi++)
      #pragma unroll
      for (int ni = 0; ni < 2; ni++)
        acc[mi][ni] = __builtin_amdgcn_mfma_f32_16x16x32_bf16(af[mi], bfr[ni], acc[mi][ni], 0, 0, 0);
    __syncthreads();
  }
  #pragma unroll
  for (int mi = 0; mi < 2; mi++){
    #pragma unroll
    for (int ni = 0; ni < 2; ni++){
      #pragma unroll
      for (int r = 0; r < 4; r++){
        int n  = n0 + wy + mi*16 + q*4 + r;
        int jj = j0 + wx + ni*16 + l15;
        if (n < N && jj < NC){
          float v = acc[mi][ni][r] + bias[jj];
          stv(&Cout[(size_t)n*ldc + jj], v);
        }
      }
    }
  }
}

// ---------------- fused post GEMM (R8 proven config): 64 rows/block ----------------
// grid (1, NB, T). COLS = F per tower; K4F = 4*COLS; agg lda = 16*COLS (T=4 towers).
template<int COLS, int KX>
__global__ __launch_bounds__(256) void k_postx(
    const bf16* __restrict__ X,        // [N, KX]
    const bf16* __restrict__ agg,      // [N, 16*COLS]
    const bf16* __restrict__ WxT,      // [4*COLS, KX]
    const bf16* __restrict__ Wagg3,    // [T][3*COLS][K4F]
    const float* __restrict__ bias,    // [4*COLS]
    const float* __restrict__ scal,
    bf16* __restrict__ Cout, int ldc, int N)
{
  constexpr int K4F = 4*COLS;
  constexpr int ROWS3 = 3*COLS;
  constexpr int NI = COLS/32;          // 2 (COLS=64) or 1 (COLS=32)
  constexpr int LDA_AGG = 16*COLS;
  __shared__ __align__(16) bf16 As[64*40];
  __shared__ __align__(16) bf16 Bs[ROWS3*40];
  int z = blockIdx.z;
  int n0 = blockIdx.y*64;
  int tid = threadIdx.x;
  int srow = tid>>2, skoff = (tid&3)*8;
  int wave = tid>>6, lane = tid&63;
  int wy = (wave>>1)*32;
  int wx = (wave&1)*(COLS/2);
  int l15 = lane&15, q = lane>>4;
  f32x4 accx[2][NI] = {};
  f32x4 acc[2][NI][3] = {};
  // ---- phase 1: X @ WxT (tower slice) ----
  const bf16* Bx = WxT + (size_t)z*COLS*KX;
  for (int k0 = 0; k0 < KX; k0 += 32){
    uint4 av = {0,0,0,0};
    int ar = n0 + srow;
    if (ar < N) av = *(const uint4*)(X + (size_t)ar*KX + k0 + skoff);
    *(uint4*)&As[srow*40 + skoff] = av;
    if (srow < COLS){
      uint4 bv = *(const uint4*)(Bx + (size_t)srow*KX + k0 + skoff);
      *(uint4*)&Bs[srow*40 + skoff] = bv;
    }
    __syncthreads();
    short8 af[2];
    #pragma unroll
    for (int i = 0; i < 2; i++)
      af[i] = *(const short8*)&As[(wy + i*16 + l15)*40 + q*8];
    #pragma unroll
    for (int ni = 0; ni < NI; ni++){
      short8 bfr = *(const short8*)&Bs[(wx + ni*16 + l15)*40 + q*8];
      #pragma unroll
      for (int mi = 0; mi < 2; mi++)
        accx[mi][ni] = __builtin_amdgcn_mfma_f32_16x16x32_bf16(af[mi], bfr, accx[mi][ni], 0, 0, 0);
    }
    __syncthreads();
  }
  // ---- phase 2: agg @ Wagg3 (3 scaler blocks) ----
  const bf16* Az = agg + (size_t)z*K4F;
  const bf16* Bz = Wagg3 + (size_t)z*ROWS3*K4F;
  for (int k0 = 0; k0 < K4F; k0 += 32){
    uint4 av = {0,0,0,0};
    int ar = n0 + srow;
    if (ar < N) av = *(const uint4*)(Az + (size_t)ar*LDA_AGG + k0 + skoff);
    *(uint4*)&As[srow*40 + skoff] = av;
    for (int r = srow; r < ROWS3; r += 64){
      uint4 bv = *(const uint4*)(Bz + (size_t)r*K4F + k0 + skoff);
      *(uint4*)&Bs[r*40 + skoff] = bv;
    }
    __syncthreads();
    short8 af[2];
    #pragma unroll
    for (int i = 0; i < 2; i++)
      af[i] = *(const short8*)&As[(wy + i*16 + l15)*40 + q*8];
    #pragma unroll
    for (int s = 0; s < 3; s++){
      #pragma unroll
      for (int ni = 0; ni < NI; ni++){
        short8 bfr = *(const short8*)&Bs[(s*COLS + wx + ni*16 + l15)*40 + q*8];
        #pragma unroll
        for (int mi = 0; mi < 2; mi++)
          acc[mi][ni][s] = __builtin_amdgcn_mfma_f32_16x16x32_bf16(af[mi], bfr, acc[mi][ni][s], 0, 0, 0);
      }
    }
    __syncthreads();
  }
  #pragma unroll
  for (int mi = 0; mi < 2; mi++){
    #pragma unroll
    for (int ni = 0; ni < NI; ni++){
      int jj = wx + ni*16 + l15;
      int jg = z*COLS + jj;
      float bj = bias[jg];
      #pragma unroll
      for (int r = 0; r < 4; r++){
        int n = n0 + wy + mi*16 + q*4 + r;
        if (n < N){
          float s1 = scal[2*n], s2 = scal[2*n+1];
          float v = bj + accx[mi][ni][r]
                  + acc[mi][ni][0][r] + s1*acc[mi][ni][1][r] + s2*acc[mi][ni][2][r];
          Cout[(size_t)n*ldc + jg] = __float2bfloat16(v);
        }
      }
    }
  }
}

// ---------------- per-node PNA aggregation -> agg [N, T*4F] bf16 + scal ----------------
// node per wave; 8-edge unroll; stats computed on q and p-shifted at the end
// (m = p+q, p lane-constant: Σm=deg·p+Σq, Σm²=Σq²+2pΣq+deg·p², min m=p+min q).
template<int NC, int F>
__global__ __launch_bounds__(256) void k_agg(const bf16* __restrict__ PQ,
    const int* __restrict__ ssrc, const int* __restrict__ offs,
    const float* __restrict__ avgp,
    bf16* __restrict__ agg, float* __restrict__ scal, int N){
  constexpr int VEC = NC/64;
  int wave = threadIdx.x>>6, lane = threadIdx.x&63;
  int n = blockIdx.x*4 + wave;
  if (n >= N) return;
  int c0 = lane*VEC;
  float p[VEC];
  ldbf<VEC>(PQ + (size_t)n*2*NC + c0, p);
  int s0 = offs[n], s1 = offs[n+1];
  float sum[VEC], sq[VEC], mn[VEC], mx[VEC];
  #pragma unroll
  for (int v=0;v<VEC;v++){ sum[v]=0.f; sq[v]=0.f; mn[v]=FLT_MAX; mx[v]=-FLT_MAX; }
  const bf16* Q = PQ + NC + c0;
  int i = s0;
  for (; i+7 < s1; i += 8){
    int se[8];
    #pragma unroll
    for (int u=0;u<8;u++) se[u] = ssrc[i+u];
    float qv[8][VEC];
    #pragma unroll
    for (int u=0;u<8;u++) ldbf<VEC>(Q + (size_t)se[u]*2*NC, qv[u]);
    #pragma unroll
    for (int u=0;u<8;u++){
      #pragma unroll
      for (int v=0;v<VEC;v++){
        float qq = qv[u][v];
        sum[v] += qq; sq[v] = fmaf(qq,qq,sq[v]);
        mn[v] = fminf(mn[v], qq); mx[v] = fmaxf(mx[v], qq);
      }
    }
  }
  for (; i+3 < s1; i += 4){
    int se[4];
    #pragma unroll
    for (int u=0;u<4;u++) se[u] = ssrc[i+u];
    float qv[4][VEC];
    #pragma unroll
    for (int u=0;u<4;u++) ldbf<VEC>(Q + (size_t)se[u]*2*NC, qv[u]);
    #pragma unroll
    for (int u=0;u<4;u++){
      #pragma unroll
      for (int v=0;v<VEC;v++){
        float qq = qv[u][v];
        sum[v] += qq; sq[v] = fmaf(qq,qq,sq[v]);
        mn[v] = fminf(mn[v], qq); mx[v] = fmaxf(mx[v], qq);
      }
    }
  }
  for (; i < s1; i++){
    int sa = ssrc[i];
    float qa[VEC];
    ldbf<VEC>(Q + (size_t)sa*2*NC, qa);
    #pragma unroll
    for (int v=0;v<VEC;v++){
      float qq = qa[v];
      sum[v]+=qq; sq[v]=fmaf(qq,qq,sq[v]); mn[v]=fminf(mn[v],qq); mx[v]=fmaxf(mx[v],qq);
    }
  }
  int deg = s1-s0;
  float degf = (float)deg;
  float degc = fmaxf(degf, 1.f);
  unsigned short um[VEC], un[VEC], ux[VEC], us[VEC];
  #pragma unroll
  for (int v=0;v<VEC;v++){
    float pv = p[v];
    float sum_m = fmaf(degf, pv, sum[v]);
    float sq_m  = sq[v] + 2.f*pv*sum[v] + degf*pv*pv;
    float mean = sum_m/degc;
    float var = fmaxf(sq_m/degc - mean*mean, 0.f);
    float sd = sqrtf(var + 1e-5f);
    float mnv = deg>0 ? pv + mn[v] : 0.f;
    float mxv = deg>0 ? pv + mx[v] : 0.f;
    um[v]=f2bu(mean); un[v]=f2bu(mnv); ux[v]=f2bu(mxv); us[v]=f2bu(sd);
  }
  int t = c0 / F, f0 = c0 % F;
  bf16* base = agg + (size_t)n*4*NC + (size_t)t*4*F + f0;
  if constexpr (VEC==4){
    *(ushort4*)(base)       = make_ushort4(um[0],um[1],um[2],um[3]);
    *(ushort4*)(base + F)   = make_ushort4(un[0],un[1],un[2],un[3]);
    *(ushort4*)(base + 2*F) = make_ushort4(ux[0],ux[1],ux[2],ux[3]);
    *(ushort4*)(base + 3*F) = make_ushort4(us[0],us[1],us[2],us[3]);
  } else {
    *(ushort2*)(base)       = make_ushort2(um[0],um[1]);
    *(ushort2*)(base + F)   = make_ushort2(un[0],un[1]);
    *(ushort2*)(base + 2*F) = make_ushort2(ux[0],ux[1]);
    *(ushort2*)(base + 3*F) = make_ushort2(us[0],us[1]);
  }
  if (lane==0){
    float dlog = logf(degc + 1.f);
    float avg = *avgp;
    scal[2*n]   = dlog/avg;
    scal[2*n+1] = avg/dlog;
  }
}

// ---------------- batch norm: two-phase, no hot atomics ----------------
template<int C>
__global__ __launch_bounds__(256) void k_bn_part(const float* __restrict__ h,
                                                 float* __restrict__ part, int N){
  constexpr int C4 = C/4;
  constexpr int RG = 256/C4;
  constexpr int RPB = 128;
  int c4 = threadIdx.x % C4, rg = threadIdx.x / C4;
  int n0 = blockIdx.x*RPB;
  int n1 = min(n0 + RPB, N);
  float4 s = {0,0,0,0}, q = {0,0,0,0};
  for (int n = n0 + rg; n < n1; n += RG){
    float4 v = *(const float4*)(h + (size_t)n*C + c4*4);
    v.x = nanfix(v.x); v.y = nanfix(v.y); v.z = nanfix(v.z); v.w = nanfix(v.w);
    s.x += v.x; s.y += v.y; s.z += v.z; s.w += v.w;
    q.x += v.x*v.x; q.y += v.y*v.y; q.z += v.z*v.z; q.w += v.w*v.w;
  }
  __shared__ float4 ssum[256], ssq[256];
  ssum[threadIdx.x] = s; ssq[threadIdx.x] = q;
  __syncthreads();
  if (rg == 0){
    #pragma unroll
    for (int g = 1; g < RG; g++){
      float4 o = ssum[g*C4 + c4];
      s.x += o.x; s.y += o.y; s.z += o.z; s.w += o.w;
      float4 p = ssq[g*C4 + c4];
      q.x += p.x; q.y += p.y; q.z += p.z; q.w += p.w;
    }
    float* dst = part + (size_t)blockIdx.x*2*C;
    *(float4*)(dst + c4*4)     = s;
    *(float4*)(dst + C + c4*4) = q;
  }
}

template<int C>
__global__ __launch_bounds__(256) void k_bn_final(const float* __restrict__ part, int PB,
                                                  float* __restrict__ stats){
  int c = blockIdx.x*256 + threadIdx.x;
  if (c >= 2*C) return;
  int CH = gridDim.y;
  int per = (PB + CH - 1)/CH;
  int p0 = blockIdx.y*per, p1 = min(p0 + per, PB);
  float acc = 0.f;
  int p = p0;
  for (; p+4 <= p1; p += 4){
    acc += part[(size_t)p*2*C + c] + part[(size_t)(p+1)*2*C + c]
         + part[(size_t)(p+2)*2*C + c] + part[(size_t)(p+3)*2*C + c];
  }
  for (; p < p1; p++) acc += part[(size_t)p*2*C + c];
  atomicAdd(&stats[c], acc);
}

template<typename TO, int C>
__global__ void k_bn_apply(const float* __restrict__ h, const float* __restrict__ stats,
     const float* __restrict__ g, const float* __restrict__ b,
     TO* __restrict__ out, int N){
  int idx = blockIdx.x*blockDim.x + threadIdx.x;   // quad index
  if (idx >= N*(C/4)) return;
  int c = (idx % (C/4))*4;
  float fn = (float)N;
  float4 v = *(const float4*)(h + (size_t)idx*4);
  float r[4];
  #pragma unroll
  for (int k = 0; k < 4; k++){
    float m = stats[c+k]/fn;
    float var = fmaxf(stats[C+c+k]/fn - m*m, 0.f);
    float inv = rsqrtf(var + 1e-5f);
    float vv = nanfix(((const float*)&v)[k]);
    r[k] = fmaxf(g[c+k]*(vv - m)*inv + b[c+k], 0.f);
  }
  if constexpr (sizeof(TO) == 4){
    float4 o = {r[0], r[1], r[2], r[3]};
    *(float4*)((float*)out + (size_t)idx*4) = o;
  } else {
    ushort4 o = make_ushort4(f2bu(r[0]), f2bu(r[1]), f2bu(r[2]), f2bu(r[3]));
    *(ushort4*)((bf16*)out + (size_t)idx*4) = o;
  }
}

static inline int cdiv(int a, int b){ return (a + b - 1)/b; }

extern "C" void kernel_launch(void* const* d_in, const int* in_sizes, int n_in,
                              void* d_out, int out_size, void* d_ws, size_t ws_size,
                              hipStream_t stream){
  const int IN = 128, HID = 256, T = 4, F1 = 64, F2 = 32;
  const int N = in_sizes[0]/IN;
  const int E = in_sizes[1]/2;
  const int NC1 = T*F1;        // 256
  const int NC2 = T*F2;        // 128

  const float* x      = (const float*)d_in[0];
  const int*   ei     = (const int*)  d_in[1];
  const int*   srcE   = ei;
  const int*   tgtE   = ei + E;
  const float* avgp   = (const float*)d_in[2];
  const float* pre1W  = (const float*)d_in[3];
  const float* pre1b  = (const float*)d_in[4];
  const float* post1W = (const float*)d_in[5];
  const float* post1b = (const float*)d_in[6];
  const float* lin1W  = (const float*)d_in[7];
  const float* lin1b  = (const float*)d_in[8];
  const float* bn1g   = (const float*)d_in[9];
  const float* bn1b   = (const float*)d_in[10];
  const float* pre2W  = (const float*)d_in[11];
  const float* pre2b  = (const float*)d_in[12];
  const float* post2W = (const float*)d_in[13];
  const float* post2b = (const float*)d_in[14];
  const float* lin2W  = (const float*)d_in[15];
  const float* lin2b  = (const float*)d_in[16];
  const float* bn2g   = (const float*)d_in[17];
  const float* bn2b   = (const float*)d_in[18];

  // ---- workspace carve ----
  char* w = (char*)d_ws;
  auto alloc = [&](size_t bytes)->void*{
    void* p = (void*)w; w += (bytes + 255) & ~(size_t)255; return p;
  };
  bf16* WpqT1  = (bf16*)alloc((size_t)2*NC1*IN*2);    float* bpq1   = (float*)alloc(2*NC1*4);
  bf16* WxT1   = (bf16*)alloc((size_t)NC1*IN*2);      float* bpost1 = (float*)alloc(NC1*4);
  bf16* Wagg31 = (bf16*)alloc((size_t)T*3*F1*4*F1*2);
  bf16* lin1WT = (bf16*)alloc((size_t)HID*NC1*2);
  bf16* WpqT2  = (bf16*)alloc((size_t)2*NC2*HID*2);   float* bpq2   = (float*)alloc(2*NC2*4);
  bf16* WxT2   = (bf16*)alloc((size_t)NC2*HID*2);     float* bpost2 = (float*)alloc(NC2*4);
  bf16* Wagg32 = (bf16*)alloc((size_t)T*3*F2*4*F2*2);
  bf16* lin2WT = (bf16*)alloc((size_t)128*NC2*2);
  // zero region: deg_i | cnt | stats (one memset)
  int* deg_i   = (int*)alloc((size_t)N*4);
  int* cnt     = (int*)alloc((size_t)N*4);
  float* stats = (float*)alloc(1024*4);
  size_t zbytes = (size_t)((char*)stats - (char*)deg_i) + 1024*4;
  int* offs    = (int*)alloc((size_t)(N+1)*4);
  int* bsum    = (int*)alloc((size_t)cdiv(N,256)*4);
  int* ssrc    = (int*)alloc((size_t)E*4);
  bf16* x_bf   = (bf16*)alloc((size_t)N*IN*2);
  bf16* PQ     = (bf16*)alloc((size_t)N*512*2);
  bf16* aggb   = (bf16*)alloc((size_t)N*4*NC1*2);    // L2 reuses prefix [N, 4*NC2]
  float* scal  = (float*)alloc((size_t)N*2*4);
  bf16* postbb = (bf16*)alloc((size_t)N*256*2);
  float* hpre  = (float*)alloc((size_t)N*256*4);
  bf16* h1b    = (bf16*)alloc((size_t)N*256*2);
  int PB = cdiv(N,128);
  float* part  = (float*)alloc((size_t)PB*512*4);

  hipMemsetAsync(deg_i, 0, zbytes, stream);

  // ---- setup: all weight repacks + x conversion (one dispatch) ----
  int sgx = cdiv(T*3*F1*4*F1, 256);   // 768 blocks covers the largest segment
  SetupArgs sa = { pre1W, pre1b, post1W, post1b, lin1W,
                   pre2W, pre2b, post2W, post2b, lin2W,
                   x,
                   WpqT1, WxT1, Wagg31, lin1WT,
                   WpqT2, WxT2, Wagg32, lin2WT,
                   x_bf,
                   bpq1, bpost1, bpq2, bpost2,
                   N*IN/4, sgx*256 };
  k_setup<<<dim3(sgx, 9),256,0,stream>>>(sa);

  // ---- counting sort of edges by target (parallel scan) ----
  int NBs = cdiv(N,256);
  k_deg<<<cdiv(E,256),256,0,stream>>>(tgtE, deg_i, E);
  k_scan1<<<NBs,256,0,stream>>>(deg_i, bsum, N);
  k_scan2<<<1,1024,0,stream>>>(bsum, NBs);
  k_scan3<<<NBs,256,0,stream>>>(deg_i, bsum, offs, N);
  k_scatter<<<cdiv(E,256),256,0,stream>>>(srcE, tgtE, offs, cnt, ssrc, E);

  int NB = cdiv(N,64);

  // ================= Layer 1 =================
  k_mgemm<bf16><<<dim3(8,NB),256,0,stream>>>(x_bf, IN, WpqT1, bpq1, PQ, 512, N, IN, 512);
  k_agg<256,64><<<cdiv(N,4),256,0,stream>>>(PQ, ssrc, offs, avgp, aggb, scal, N);
  k_postx<64,128><<<dim3(1,NB,T),256,0,stream>>>(x_bf, aggb, WxT1, Wagg31, bpost1, scal,
                                                 postbb, NC1, N);
  k_mgemm<float><<<dim3(4,NB),256,0,stream>>>(postbb, NC1, lin1WT, lin1b, hpre, HID, N, NC1, HID);
  k_bn_part<256><<<PB,256,0,stream>>>(hpre, part, N);
  k_bn_final<256><<<dim3(2,4),256,0,stream>>>(part, PB, stats);
  k_bn_apply<bf16,256><<<cdiv(N*64,256),256,0,stream>>>(hpre, stats, bn1g, bn1b, h1b, N);

  // ================= Layer 2 =================
  k_mgemm<bf16><<<dim3(4,NB),256,0,stream>>>(h1b, HID, WpqT2, bpq2, PQ, 256, N, HID, 256);
  k_agg<128,32><<<cdiv(N,4),256,0,stream>>>(PQ, ssrc, offs, avgp, aggb, scal, N);
  k_postx<32,256><<<dim3(1,NB,T),256,0,stream>>>(h1b, aggb, WxT2, Wagg32, bpost2, scal,
                                                 postbb, NC2, N);
  k_mgemm<float><<<dim3(2,NB),256,0,stream>>>(postbb, NC2, lin2WT, lin2b, hpre, 128, N, NC2, 128);
  k_bn_part<128><<<PB,256,0,stream>>>(hpre, part, N);
  k_bn_final<128><<<dim3(1,4),256,0,stream>>>(part, PB, stats + 512);
  k_bn_apply<float,128><<<cdiv(N*32,256),256,0,stream>>>(hpre, stats + 512, bn2g, bn2b, (float*)d_out, N);
}